// Round 1
// baseline (3012.788 us; speedup 1.0000x reference)
//
#include <hip/hip_runtime.h>
#include <hip/hip_bf16.h>
#include <math.h>

// Problem constants
#define GQA_B   2
#define GQA_T   2048
#define GQA_E   2048      // embed dim
#define GQA_HQ  32        // query heads
#define GQA_HKV 8         // kv heads
#define GQA_HD  64        // head dim
#define GQA_EKV 1024      // 2*HKV*HD
#define GQA_M   (GQA_B * GQA_T)   // 4096 rows

// ---------------------------------------------------------------------------
// GEMM: C(M,N) = A(M,K) @ B(N,K)^T   (torch Linear: y = x @ W.T, W is (out,in))
// fp32, 128x128 tile, BK=16, 256 threads, 8x8 microtile per thread.
// ---------------------------------------------------------------------------
#define TILE_BM 128
#define TILE_BN 128
#define TILE_BK 16

__global__ __launch_bounds__(256) void gqa_gemm_nt_f32(
    const float* __restrict__ A, const float* __restrict__ B,
    float* __restrict__ C, int M, int N, int K) {
  __shared__ float As[TILE_BK][TILE_BM + 4];
  __shared__ float Bs[TILE_BK][TILE_BN + 4];
  const int tid = threadIdx.x;
  const int tx = tid & 15;   // 0..15 -> N direction
  const int ty = tid >> 4;   // 0..15 -> M direction
  const int bm0 = blockIdx.y * TILE_BM;
  const int bn0 = blockIdx.x * TILE_BN;

  float acc[8][8];
#pragma unroll
  for (int i = 0; i < 8; ++i)
#pragma unroll
    for (int j = 0; j < 8; ++j) acc[i][j] = 0.f;

  for (int k0 = 0; k0 < K; k0 += TILE_BK) {
    // Stage A tile: 128 rows x 16 k = 512 float4, 2 per thread (k-contiguous loads)
#pragma unroll
    for (int p = 0; p < 2; ++p) {
      int f = p * 256 + tid;
      int row = f >> 2;      // 0..127
      int q4  = f & 3;       // which float4 along k
      float4 v = *(const float4*)(A + (size_t)(bm0 + row) * K + k0 + q4 * 4);
      As[q4 * 4 + 0][row] = v.x;
      As[q4 * 4 + 1][row] = v.y;
      As[q4 * 4 + 2][row] = v.z;
      As[q4 * 4 + 3][row] = v.w;
    }
#pragma unroll
    for (int p = 0; p < 2; ++p) {
      int f = p * 256 + tid;
      int row = f >> 2;
      int q4  = f & 3;
      float4 v = *(const float4*)(B + (size_t)(bn0 + row) * K + k0 + q4 * 4);
      Bs[q4 * 4 + 0][row] = v.x;
      Bs[q4 * 4 + 1][row] = v.y;
      Bs[q4 * 4 + 2][row] = v.z;
      Bs[q4 * 4 + 3][row] = v.w;
    }
    __syncthreads();

#pragma unroll
    for (int kk = 0; kk < TILE_BK; ++kk) {
      float a[8], b[8];
      *(float4*)&a[0] = *(const float4*)&As[kk][ty * 8];
      *(float4*)&a[4] = *(const float4*)&As[kk][ty * 8 + 4];
      *(float4*)&b[0] = *(const float4*)&Bs[kk][tx * 8];
      *(float4*)&b[4] = *(const float4*)&Bs[kk][tx * 8 + 4];
#pragma unroll
      for (int i = 0; i < 8; ++i)
#pragma unroll
        for (int j = 0; j < 8; ++j) acc[i][j] += a[i] * b[j];
    }
    __syncthreads();
  }

#pragma unroll
  for (int i = 0; i < 8; ++i) {
    float* crow = C + (size_t)(bm0 + ty * 8 + i) * N + bn0 + tx * 8;
    *(float4*)(crow + 0) = make_float4(acc[i][0], acc[i][1], acc[i][2], acc[i][3]);
    *(float4*)(crow + 4) = make_float4(acc[i][4], acc[i][5], acc[i][6], acc[i][7]);
  }
}

// ---------------------------------------------------------------------------
// Causal GQA flash attention, fp32.
// Q buffer: (B,T,2048), col = hq*64 + d
// KV buffer: (B,T,1024): K col = hkv*64 + d ; V col = 512 + hkv*64 + d
// O buffer: (B,T,2048), col = hq*64 + d
// Grid: (T/64, HQ, B). Block: 256 threads.
// Thread (r = tid/4, c = tid%4): owns S columns cs = 4j+c (j=0..15) and
// O columns d = c*16 + j. Row-wide max/sum via __shfl_xor width 4.
// ---------------------------------------------------------------------------
__global__ __launch_bounds__(256) void gqa_flash_attn_f32(
    const float* __restrict__ Q, const float* __restrict__ KV,
    float* __restrict__ O) {
  const int T = GQA_T, EQ = GQA_E, EKV = GQA_EKV;
  const int qt0 = blockIdx.x * 64;
  const int hq  = blockIdx.y;
  const int b   = blockIdx.z;
  const int hkv = hq >> 2;   // G = 4

  __shared__ float Qs[64][68];
  __shared__ float Ks[64][68];
  __shared__ float Vs[64][68];
  __shared__ float Ps[64][68];

  const int tid = threadIdx.x;
  const int r = tid >> 2;   // 0..63 local q row
  const int c = tid & 3;    // 0..3 column group

  // Load Q tile (64 rows x 64 cols)
  {
    const float* qbase = Q + ((size_t)b * T + qt0) * EQ + hq * GQA_HD;
#pragma unroll
    for (int p = 0; p < 4; ++p) {
      int f = p * 256 + tid;        // float4 index 0..1023
      int row = f >> 4, col4 = f & 15;
      *(float4*)&Qs[row][col4 * 4] =
          *(const float4*)(qbase + (size_t)row * EQ + col4 * 4);
    }
  }

  float acc[16];
#pragma unroll
  for (int j = 0; j < 16; ++j) acc[j] = 0.f;
  float m = -INFINITY, l = 0.f;
  const float scale = 0.125f;   // 1/sqrt(64)

  const float* kbase = KV + (size_t)b * T * EKV + hkv * GQA_HD;
  const float* vbase = kbase + GQA_HKV * GQA_HD;  // +512

  const int nt = blockIdx.x + 1;   // s tiles 0..qt0/64
  for (int t = 0; t < nt; ++t) {
    const int s0 = t * 64;
    __syncthreads();  // previous tile's K/V reads done before overwrite
#pragma unroll
    for (int p = 0; p < 4; ++p) {
      int f = p * 256 + tid;
      int row = f >> 4, col4 = f & 15;
      *(float4*)&Ks[row][col4 * 4] =
          *(const float4*)(kbase + (size_t)(s0 + row) * EKV + col4 * 4);
      *(float4*)&Vs[row][col4 * 4] =
          *(const float4*)(vbase + (size_t)(s0 + row) * EKV + col4 * 4);
    }
    __syncthreads();

    // S = Q K^T for this thread's 16 columns (cs = 4j + c)
    float pj[16];
#pragma unroll
    for (int j = 0; j < 16; ++j) pj[j] = 0.f;
#pragma unroll
    for (int d4 = 0; d4 < 16; ++d4) {
      float4 qv = *(const float4*)&Qs[r][d4 * 4];
#pragma unroll
      for (int j = 0; j < 16; ++j) {
        float4 kv4 = *(const float4*)&Ks[4 * j + c][d4 * 4];
        pj[j] += qv.x * kv4.x + qv.y * kv4.y + qv.z * kv4.z + qv.w * kv4.w;
      }
    }

    // causal mask + scale, tile row max
    float mt = -INFINITY;
#pragma unroll
    for (int j = 0; j < 16; ++j) {
      int cs = s0 + 4 * j + c;
      pj[j] = (cs <= qt0 + r) ? pj[j] * scale : -INFINITY;
      mt = fmaxf(mt, pj[j]);
    }
    mt = fmaxf(mt, __shfl_xor(mt, 1, 4));
    mt = fmaxf(mt, __shfl_xor(mt, 2, 4));

    const float mnew = fmaxf(m, mt);
    const float alpha = __expf(m - mnew);   // m=-inf first tile -> alpha=0

    float lt = 0.f;
#pragma unroll
    for (int j = 0; j < 16; ++j) {
      float p = __expf(pj[j] - mnew);       // masked -> exp(-inf)=0
      pj[j] = p;
      lt += p;
    }
    lt += __shfl_xor(lt, 1, 4);
    lt += __shfl_xor(lt, 2, 4);

    l = l * alpha + lt;
    m = mnew;
#pragma unroll
    for (int j = 0; j < 16; ++j) acc[j] *= alpha;

    // Share P within the wave via LDS (row r served by lanes 4r..4r+3 of the
    // same wave; DS ops from one wave complete in order -> no barrier needed)
#pragma unroll
    for (int j = 0; j < 16; ++j) Ps[r][4 * j + c] = pj[j];

    // O += P V : this thread owns d = c*16 .. c*16+15
#pragma unroll
    for (int s = 0; s < 64; ++s) {
      float p = Ps[r][s];
#pragma unroll
      for (int jj = 0; jj < 4; ++jj) {
        float4 vv = *(const float4*)&Vs[s][c * 16 + jj * 4];
        acc[jj * 4 + 0] += p * vv.x;
        acc[jj * 4 + 1] += p * vv.y;
        acc[jj * 4 + 2] += p * vv.z;
        acc[jj * 4 + 3] += p * vv.w;
      }
    }
  }

  // epilogue
  const float inv = 1.f / l;
  float* obase = O + ((size_t)b * T + qt0 + r) * EQ + hq * GQA_HD + c * 16;
#pragma unroll
  for (int jj = 0; jj < 4; ++jj) {
    float4 v = make_float4(acc[jj * 4 + 0] * inv, acc[jj * 4 + 1] * inv,
                           acc[jj * 4 + 2] * inv, acc[jj * 4 + 3] * inv);
    *(float4*)(obase + jj * 4) = v;
  }
}

// ---------------------------------------------------------------------------
extern "C" void kernel_launch(void* const* d_in, const int* in_sizes, int n_in,
                              void* d_out, int out_size, void* d_ws, size_t ws_size,
                              hipStream_t stream) {
  const float* x   = (const float*)d_in[0];   // (B,T,E)
  const float* Wq  = (const float*)d_in[1];   // (E,E)
  const float* Wkv = (const float*)d_in[2];   // (1024,E)
  const float* Wo  = (const float*)d_in[3];   // (E,E)
  float* out = (float*)d_out;                  // (B,T,E)

  float* qbuf  = (float*)d_ws;                         // 4096*2048 f32 = 32MB
  float* kvbuf = qbuf + (size_t)GQA_M * GQA_E;         // 4096*1024 f32 = 16MB
  float* att   = kvbuf + (size_t)GQA_M * GQA_EKV;      // 4096*2048 f32 = 32MB

  // Q = x @ Wq^T : M=4096, N=2048, K=2048
  gqa_gemm_nt_f32<<<dim3(GQA_E / TILE_BN, GQA_M / TILE_BM), 256, 0, stream>>>(
      x, Wq, qbuf, GQA_M, GQA_E, GQA_E);
  // KV = x @ Wkv^T : M=4096, N=1024, K=2048
  gqa_gemm_nt_f32<<<dim3(GQA_EKV / TILE_BN, GQA_M / TILE_BM), 256, 0, stream>>>(
      x, Wkv, kvbuf, GQA_M, GQA_EKV, GQA_E);
  // attention
  gqa_flash_attn_f32<<<dim3(GQA_T / 64, GQA_HQ, GQA_B), 256, 0, stream>>>(
      qbuf, kvbuf, att);
  // out = att @ Wo^T : M=4096, N=2048, K=2048
  gqa_gemm_nt_f32<<<dim3(GQA_E / TILE_BN, GQA_M / TILE_BM), 256, 0, stream>>>(
      att, Wo, out, GQA_M, GQA_E, GQA_E);
}

// Round 3
// 502.304 us; speedup vs baseline: 5.9979x; 5.9979x over previous
//
#include <hip/hip_runtime.h>
#include <hip/hip_bf16.h>
#include <math.h>

// Problem constants
#define GQA_B   2
#define GQA_T   2048
#define GQA_E   2048      // embed dim
#define GQA_HQ  32        // query heads
#define GQA_HKV 8         // kv heads
#define GQA_HD  64        // head dim
#define GQA_EKV 1024      // 2*HKV*HD
#define GQA_M   (GQA_B * GQA_T)   // 4096 rows

typedef short  bf16x8 __attribute__((ext_vector_type(8)));
typedef float  f32x4  __attribute__((ext_vector_type(4)));

// fp32 -> bf16 round-to-nearest-even (bit trick)
__device__ __forceinline__ ushort f2b(float f) {
  union { float f; unsigned u; } c; c.f = f;
  unsigned u = c.u;
  u += 0x7fffu + ((u >> 16) & 1u);
  return (ushort)(u >> 16);
}

// ---------------------------------------------------------------------------
// fp32 -> bf16 conversion, vectorized (float4 in, ushort4 out), grid-stride
// ---------------------------------------------------------------------------
__global__ __launch_bounds__(256) void cvt_f32_bf16(
    const float* __restrict__ src, ushort* __restrict__ dst, int n4) {
  int i = blockIdx.x * blockDim.x + threadIdx.x;
  const int stride = gridDim.x * blockDim.x;
  for (; i < n4; i += stride) {
    float4 v = *(const float4*)(src + (size_t)i * 4);
    ushort4 o;
    o.x = f2b(v.x); o.y = f2b(v.y); o.z = f2b(v.z); o.w = f2b(v.w);
    *(ushort4*)(dst + (size_t)i * 4) = o;
  }
}

// ---------------------------------------------------------------------------
// bf16 MFMA GEMM (NT): C(M,N) = A(M,K) @ B(N,K)^T, A/B bf16 K-contiguous.
// 128x128 tile, BK=32, 256 threads (4 waves, each 64x64 out = 4x4 frags of
// 16x16x32). LDS rows padded +8 bf16 (80 B stride -> 2-way/free frag reads).
// CT = ushort (bf16 out) or float (fp32 out).
// m97-style 2-barrier loop; global loads hoisted above the first barrier.
// ---------------------------------------------------------------------------
__device__ __forceinline__ void store_out(ushort* p, float v) { *p = f2b(v); }
__device__ __forceinline__ void store_out(float* p, float v)  { *p = v; }

template <typename CT>
__global__ __launch_bounds__(256) void gemm_nt_bf16(
    const ushort* __restrict__ A, const ushort* __restrict__ B,
    CT* __restrict__ C, int M, int N, int K) {
  __shared__ __align__(16) ushort As[128 * 40];   // row stride 40 elems = 80 B
  __shared__ __align__(16) ushort Bs[128 * 40];
  const int tid = threadIdx.x;
  const int l  = tid & 63;
  const int w  = tid >> 6;
  const int lm = l & 15;     // MFMA m/n index
  const int lg = l >> 4;     // MFMA k-octet
  const int wm = w & 1;      // wave tile coords (2x2 waves of 64x64)
  const int wn = w >> 1;
  const int bm = blockIdx.y * 128;
  const int bn = blockIdx.x * 128;

  const int srow = tid >> 2;            // staging row 0..63 (and +64)
  const int scol = (tid & 3) * 8;       // staging k-elem offset
  const ushort* Ag = A + (size_t)(bm + srow) * K + scol;
  const ushort* Bg = B + (size_t)(bn + srow) * K + scol;

  f32x4 acc[4][4];
#pragma unroll
  for (int i = 0; i < 4; ++i)
#pragma unroll
    for (int j = 0; j < 4; ++j)
#pragma unroll
      for (int r = 0; r < 4; ++r) acc[i][j][r] = 0.f;

  for (int k0 = 0; k0 < K; k0 += 32) {
    int4 a0 = *(const int4*)(Ag + k0);
    int4 a1 = *(const int4*)(Ag + (size_t)64 * K + k0);
    int4 b0 = *(const int4*)(Bg + k0);
    int4 b1 = *(const int4*)(Bg + (size_t)64 * K + k0);
    __syncthreads();                       // prior iter's frag reads done
    *(int4*)(As + srow * 40 + scol)        = a0;
    *(int4*)(As + (srow + 64) * 40 + scol) = a1;
    *(int4*)(Bs + srow * 40 + scol)        = b0;
    *(int4*)(Bs + (srow + 64) * 40 + scol) = b1;
    __syncthreads();

    bf16x8 af[4], bfr[4];
#pragma unroll
    for (int mf = 0; mf < 4; ++mf)
      af[mf] = *(const bf16x8*)(As + (wm * 64 + mf * 16 + lm) * 40 + lg * 8);
#pragma unroll
    for (int nf = 0; nf < 4; ++nf)
      bfr[nf] = *(const bf16x8*)(Bs + (wn * 64 + nf * 16 + lm) * 40 + lg * 8);
#pragma unroll
    for (int mf = 0; mf < 4; ++mf)
#pragma unroll
      for (int nf = 0; nf < 4; ++nf)
        acc[mf][nf] = __builtin_amdgcn_mfma_f32_16x16x32_bf16(
            af[mf], bfr[nf], acc[mf][nf], 0, 0, 0);
  }

  // Epilogue: D-frag row = lg*4 + r, col = lm (m89-verified layout)
#pragma unroll
  for (int mf = 0; mf < 4; ++mf)
#pragma unroll
    for (int nf = 0; nf < 4; ++nf)
#pragma unroll
      for (int r = 0; r < 4; ++r) {
        const int row = bm + wm * 64 + mf * 16 + lg * 4 + r;
        const int col = bn + wn * 64 + nf * 16 + lm;
        store_out(C + (size_t)row * N + col, acc[mf][nf][r]);
      }
}

// ---------------------------------------------------------------------------
// Causal GQA flash attention, bf16 MFMA.
// Q (B,T,2048) bf16, KV (B,T,1024) bf16 (K cols 0..511, V cols 512..1023),
// O (B,T,2048) bf16. Grid (T/64, HQ, B), 256 threads = 4 waves.
// Wave w owns q-rows 16w..16w+15 of the 64-row block; all waves share
// K (row-major) and V^T (d-major) 64x64 LDS tiles, XOR-swizzled
// (byte ^= (row&7)<<4) so every frag ds_read_b128 is conflict-free.
// Softmax in fp32 on the D-fragment layout; P round-trips via a per-wave
// swizzled LDS tile to become the PV A-fragment.
// ---------------------------------------------------------------------------
__global__ __launch_bounds__(256) void gqa_attn_mfma(
    const ushort* __restrict__ Q, const ushort* __restrict__ KV,
    ushort* __restrict__ Oat) {
  const int T = GQA_T, EQ = GQA_E, EKV = GQA_EKV;
  const int qt0 = blockIdx.x * 64;
  const int hq  = blockIdx.y;
  const int b   = blockIdx.z;
  const int hkv = hq >> 2;

  __shared__ __align__(16) ushort Ks[64 * 64];       // [key][d], swizzled
  __shared__ __align__(16) ushort Vt[64 * 64];       // [d][key], swizzled
  __shared__ __align__(16) ushort Ps[4 * 16 * 64];   // per-wave [q][key], swizzled

  const int tid = threadIdx.x;
  const int w  = tid >> 6;
  const int l  = tid & 63;
  const int lm = l & 15;
  const int lg = l >> 4;

  // Hoisted Q A-fragments (rows qt0+16w+lm, k = d)
  const size_t qrow = ((size_t)b * T + qt0 + 16 * w + lm) * EQ + hq * 64;
  const bf16x8 qa0 = *(const bf16x8*)(Q + qrow + lg * 8);
  const bf16x8 qa1 = *(const bf16x8*)(Q + qrow + 32 + lg * 8);

  f32x4 oacc[4];
#pragma unroll
  for (int nd = 0; nd < 4; ++nd)
#pragma unroll
    for (int r = 0; r < 4; ++r) oacc[nd][r] = 0.f;
  float mrow[4], lrow[4];
#pragma unroll
  for (int r = 0; r < 4; ++r) { mrow[r] = -INFINITY; lrow[r] = 0.f; }

  const float scale = 0.125f;  // 1/sqrt(64)
  const size_t kvbase = (size_t)b * T * EKV + hkv * 64;

  // staging maps
  const int kf_key = tid >> 3;          // 0..31 (and +32)
  const int kf_d   = (tid & 7) * 8;     // k: 8 keys x 8 d-octets per half
  // V: key = l (per wave all 64 keys), d-octets w*8 and 32+w*8

  char* KsB = (char*)Ks;
  char* VtB = (char*)Vt;
  char* PsB = (char*)Ps + w * 2048;

  const int nt = blockIdx.x + 1;
  for (int t = 0; t < nt; ++t) {
    const int s0 = t * 64;
    // issue global loads early (overlap prior tile's PV under the barrier)
    int4 kr0 = *(const int4*)(KV + kvbase + (size_t)(s0 + kf_key) * EKV + kf_d);
    int4 kr1 = *(const int4*)(KV + kvbase + (size_t)(s0 + 32 + kf_key) * EKV + kf_d);
    int4 vr0 = *(const int4*)(KV + kvbase + 512 + (size_t)(s0 + l) * EKV + w * 8);
    int4 vr1 = *(const int4*)(KV + kvbase + 512 + (size_t)(s0 + l) * EKV + 32 + w * 8);
    __syncthreads();   // prior tile's LDS reads complete
    // K tile (b128, swizzled)
    *(int4*)(KsB + kf_key * 128 + ((kf_d * 2) ^ ((kf_key & 7) << 4))) = kr0;
    *(int4*)(KsB + (kf_key + 32) * 128 + ((kf_d * 2) ^ ((kf_key & 7) << 4))) = kr1;
    // V tile transposed (scalar b16 x16; row uniform per wave per j -> no conflict)
    {
      union { int4 v; ushort u[8]; } a, bq;
      a.v = vr0; bq.v = vr1;
#pragma unroll
      for (int j = 0; j < 8; ++j) {
        const int d0 = w * 8 + j;
        *(ushort*)(VtB + d0 * 128 + ((2 * l) ^ ((d0 & 7) << 4))) = a.u[j];
        const int d1 = 32 + w * 8 + j;
        *(ushort*)(VtB + d1 * 128 + ((2 * l) ^ ((d1 & 7) << 4))) = bq.u[j];
      }
    }
    __syncthreads();

    // ---- S = Q K^T (16 q-rows x 64 keys per wave) ----
    f32x4 sacc[4];
#pragma unroll
    for (int nf = 0; nf < 4; ++nf)
#pragma unroll
      for (int r = 0; r < 4; ++r) sacc[nf][r] = 0.f;
#pragma unroll
    for (int nf = 0; nf < 4; ++nf) {
      const int krow = nf * 16 + lm;
      const int swz = (krow & 7) << 4;
      bf16x8 kb0 = *(const bf16x8*)(KsB + krow * 128 + ((lg * 16) ^ swz));
      bf16x8 kb1 = *(const bf16x8*)(KsB + krow * 128 + ((64 + lg * 16) ^ swz));
      sacc[nf] = __builtin_amdgcn_mfma_f32_16x16x32_bf16(qa0, kb0, sacc[nf], 0, 0, 0);
      sacc[nf] = __builtin_amdgcn_mfma_f32_16x16x32_bf16(qa1, kb1, sacc[nf], 0, 0, 0);
    }

    // ---- online softmax (rows r: q = qt0+16w+lg*4+r; cols s0+nf*16+lm) ----
    const int qg = qt0 + 16 * w + lg * 4;
    if (t == nt - 1) {   // diagonal tile: mask
#pragma unroll
      for (int nf = 0; nf < 4; ++nf)
#pragma unroll
        for (int r = 0; r < 4; ++r) {
          const int sg = s0 + nf * 16 + lm;
          const float sv = sacc[nf][r] * scale;
          sacc[nf][r] = (sg <= qg + r) ? sv : -INFINITY;
        }
    } else {
#pragma unroll
      for (int nf = 0; nf < 4; ++nf)
#pragma unroll
        for (int r = 0; r < 4; ++r) sacc[nf][r] *= scale;
    }

#pragma unroll
    for (int r = 0; r < 4; ++r) {
      float m4 = fmaxf(fmaxf(sacc[0][r], sacc[1][r]), fmaxf(sacc[2][r], sacc[3][r]));
      m4 = fmaxf(m4, __shfl_xor(m4, 1, 16));
      m4 = fmaxf(m4, __shfl_xor(m4, 2, 16));
      m4 = fmaxf(m4, __shfl_xor(m4, 4, 16));
      m4 = fmaxf(m4, __shfl_xor(m4, 8, 16));
      const float mnew = fmaxf(mrow[r], m4);
      const float alpha = __expf(mrow[r] - mnew);   // first tile: exp(-inf)=0
      mrow[r] = mnew;
      float ssum = 0.f;
#pragma unroll
      for (int nf = 0; nf < 4; ++nf) {
        const float p = __expf(sacc[nf][r] - mnew);
        sacc[nf][r] = p;
        ssum += p;
      }
      ssum += __shfl_xor(ssum, 1, 16);
      ssum += __shfl_xor(ssum, 2, 16);
      ssum += __shfl_xor(ssum, 4, 16);
      ssum += __shfl_xor(ssum, 8, 16);
      lrow[r] = lrow[r] * alpha + ssum;
#pragma unroll
      for (int nd = 0; nd < 4; ++nd) oacc[nd][r] *= alpha;
    }

    // ---- P -> per-wave LDS (bf16, swizzled), wave-coherent (no barrier) ----
#pragma unroll
    for (int nf = 0; nf < 4; ++nf)
#pragma unroll
      for (int r = 0; r < 4; ++r) {
        const int q = lg * 4 + r;
        const int keyb = 2 * (nf * 16 + lm);
        *(ushort*)(PsB + q * 128 + (keyb ^ ((q & 7) << 4))) = f2b(sacc[nf][r]);
      }

    // ---- O += P V ----
    {
      const char* pw = PsB + lm * 128;
      const int pswz = (lm & 7) << 4;
      bf16x8 pa0 = *(const bf16x8*)(pw + ((lg * 16) ^ pswz));
      bf16x8 pa1 = *(const bf16x8*)(pw + ((64 + lg * 16) ^ pswz));
#pragma unroll
      for (int nd = 0; nd < 4; ++nd) {
        const int vrow = nd * 16 + lm;
        const int vswz = (vrow & 7) << 4;
        bf16x8 vb0 = *(const bf16x8*)(VtB + vrow * 128 + ((lg * 16) ^ vswz));
        bf16x8 vb1 = *(const bf16x8*)(VtB + vrow * 128 + ((64 + lg * 16) ^ vswz));
        oacc[nd] = __builtin_amdgcn_mfma_f32_16x16x32_bf16(pa0, vb0, oacc[nd], 0, 0, 0);
        oacc[nd] = __builtin_amdgcn_mfma_f32_16x16x32_bf16(pa1, vb1, oacc[nd], 0, 0, 0);
      }
    }
  }

  // ---- epilogue: O / l, bf16 out ----
  float inv[4];
#pragma unroll
  for (int r = 0; r < 4; ++r) inv[r] = 1.f / lrow[r];
  const size_t ob = ((size_t)b * T + qt0 + 16 * w + lg * 4) * EQ + hq * 64 + lm;
#pragma unroll
  for (int nd = 0; nd < 4; ++nd)
#pragma unroll
    for (int r = 0; r < 4; ++r)
      Oat[ob + (size_t)r * EQ + nd * 16] = f2b(oacc[nd][r] * inv[r]);
}

// ---------------------------------------------------------------------------
extern "C" void kernel_launch(void* const* d_in, const int* in_sizes, int n_in,
                              void* d_out, int out_size, void* d_ws, size_t ws_size,
                              hipStream_t stream) {
  const float* x   = (const float*)d_in[0];   // (B,T,E)
  const float* Wq  = (const float*)d_in[1];   // (E,E)
  const float* Wkv = (const float*)d_in[2];   // (1024,E)
  const float* Wo  = (const float*)d_in[3];   // (E,E)
  float* out = (float*)d_out;                  // (B,T,E) fp32

  // bf16 workspace layout (ushort elements); total ~76 MB
  ushort* xb   = (ushort*)d_ws;
  ushort* wqb  = xb   + (size_t)GQA_M * GQA_E;        // 8388608
  ushort* wkvb = wqb  + (size_t)GQA_E * GQA_E;        // 4194304
  ushort* wob  = wkvb + (size_t)GQA_EKV * GQA_E;      // 2097152
  ushort* qb   = wob  + (size_t)GQA_E * GQA_E;        // 4194304
  ushort* kvb  = qb   + (size_t)GQA_M * GQA_E;        // 8388608
  ushort* attb = kvb  + (size_t)GQA_M * GQA_EKV;      // 4194304

  // fp32 -> bf16 conversions
  cvt_f32_bf16<<<2048, 256, 0, stream>>>(x,   xb,   GQA_M * GQA_E / 4);
  cvt_f32_bf16<<<1024, 256, 0, stream>>>(Wq,  wqb,  GQA_E * GQA_E / 4);
  cvt_f32_bf16<<<512,  256, 0, stream>>>(Wkv, wkvb, GQA_EKV * GQA_E / 4);
  cvt_f32_bf16<<<1024, 256, 0, stream>>>(Wo,  wob,  GQA_E * GQA_E / 4);

  // Q = x @ Wq^T (bf16 out)
  gemm_nt_bf16<ushort><<<dim3(GQA_E / 128, GQA_M / 128), 256, 0, stream>>>(
      xb, wqb, qb, GQA_M, GQA_E, GQA_E);
  // KV = x @ Wkv^T (bf16 out)
  gemm_nt_bf16<ushort><<<dim3(GQA_EKV / 128, GQA_M / 128), 256, 0, stream>>>(
      xb, wkvb, kvb, GQA_M, GQA_EKV, GQA_E);
  // attention (bf16 in/out)
  gqa_attn_mfma<<<dim3(GQA_T / 64, GQA_HQ, GQA_B), 256, 0, stream>>>(
      qb, kvb, attb);
  // out = att @ Wo^T (fp32 out)
  gemm_nt_bf16<float><<<dim3(GQA_E / 128, GQA_M / 128), 256, 0, stream>>>(
      attb, wob, out, GQA_M, GQA_E, GQA_E);
}

// Round 4
// 460.710 us; speedup vs baseline: 6.5395x; 1.0903x over previous
//
#include <hip/hip_runtime.h>
#include <hip/hip_bf16.h>
#include <math.h>

// Problem constants
#define GQA_B   2
#define GQA_T   2048
#define GQA_E   2048      // embed dim
#define GQA_HQ  32        // query heads
#define GQA_HKV 8         // kv heads
#define GQA_HD  64        // head dim
#define GQA_EKV 1024      // 2*HKV*HD
#define GQA_M   (GQA_B * GQA_T)   // 4096 rows

typedef short  bf16x8 __attribute__((ext_vector_type(8)));
typedef float  f32x4  __attribute__((ext_vector_type(4)));

// async global->LDS, 16B per lane; LDS dest = wave-uniform base + lane*16
#define GLDS16(gsrc, ldst)                                                 \
  __builtin_amdgcn_global_load_lds(                                       \
      (const __attribute__((address_space(1))) void*)(gsrc),              \
      (__attribute__((address_space(3))) void*)(ldst), 16, 0, 0)

// fp32 -> bf16 round-to-nearest-even (bit trick)
__device__ __forceinline__ ushort f2b(float f) {
  union { float f; unsigned u; } c; c.f = f;
  unsigned u = c.u;
  u += 0x7fffu + ((u >> 16) & 1u);
  return (ushort)(u >> 16);
}

// ---------------------------------------------------------------------------
// fp32 -> bf16 conversion, vectorized, grid-stride
// ---------------------------------------------------------------------------
__global__ __launch_bounds__(256) void cvt_f32_bf16(
    const float* __restrict__ src, ushort* __restrict__ dst, int n4) {
  int i = blockIdx.x * blockDim.x + threadIdx.x;
  const int stride = gridDim.x * blockDim.x;
  for (; i < n4; i += stride) {
    float4 v = *(const float4*)(src + (size_t)i * 4);
    ushort4 o;
    o.x = f2b(v.x); o.y = f2b(v.y); o.z = f2b(v.z); o.w = f2b(v.w);
    *(ushort4*)(dst + (size_t)i * 4) = o;
  }
}

// ---------------------------------------------------------------------------
// bf16 MFMA GEMM (NT): C(M,N) = A(M,K) @ B(N,K)^T. m97 structure:
// 128x128 tile, BK=32, 256 threads (4 waves, 2x2 of 64x64), LINEAR LDS
// [128][32] staged via global_load_lds width=16, 2 barriers per K-step.
// ---------------------------------------------------------------------------
__device__ __forceinline__ void store_out(ushort* p, float v) { *p = f2b(v); }
__device__ __forceinline__ void store_out(float* p, float v)  { *p = v; }

template <typename CT>
__global__ __launch_bounds__(256) void gemm_nt_bf16(
    const ushort* __restrict__ A, const ushort* __restrict__ B,
    CT* __restrict__ C, int M, int N, int K) {
  __shared__ __align__(16) ushort As[128 * 32];
  __shared__ __align__(16) ushort Bs[128 * 32];
  const int tid = threadIdx.x;
  const int l  = tid & 63;
  const int w  = tid >> 6;
  const int lm = l & 15;
  const int lg = l >> 4;
  const int wm = w & 1;
  const int wn = w >> 1;
  const int bm = blockIdx.y * 128;
  const int bn = blockIdx.x * 128;

  // staging: wave w covers rows [w*32, w*32+32); lane l -> row +(l>>2),
  // k-bytes (l&3)*16. LDS flat byte = w*2048 + c*1024 + l*16 (linear match).
  const int srow = w * 32 + (l >> 2);
  const int scol = (l & 3) * 8;
  const ushort* Ag = A + (size_t)(bm + srow) * K + scol;
  const ushort* Bg = B + (size_t)(bn + srow) * K + scol;
  char* ldsA = (char*)As + w * 2048;
  char* ldsB = (char*)Bs + w * 2048;

  f32x4 acc[4][4];
#pragma unroll
  for (int i = 0; i < 4; ++i)
#pragma unroll
    for (int j = 0; j < 4; ++j)
#pragma unroll
      for (int r = 0; r < 4; ++r) acc[i][j][r] = 0.f;

  for (int k0 = 0; k0 < K; k0 += 32) {
    GLDS16(Ag + k0,                  ldsA);
    GLDS16(Ag + (size_t)16 * K + k0, ldsA + 1024);
    GLDS16(Bg + k0,                  ldsB);
    GLDS16(Bg + (size_t)16 * K + k0, ldsB + 1024);
    __syncthreads();   // drains vmcnt(0): LDS tiles complete

    bf16x8 af[4], bfr[4];
#pragma unroll
    for (int mf = 0; mf < 4; ++mf)
      af[mf] = *(const bf16x8*)(As + (wm * 64 + mf * 16 + lm) * 32 + lg * 8);
#pragma unroll
    for (int nf = 0; nf < 4; ++nf)
      bfr[nf] = *(const bf16x8*)(Bs + (wn * 64 + nf * 16 + lm) * 32 + lg * 8);
#pragma unroll
    for (int mf = 0; mf < 4; ++mf)
#pragma unroll
      for (int nf = 0; nf < 4; ++nf)
        acc[mf][nf] = __builtin_amdgcn_mfma_f32_16x16x32_bf16(
            af[mf], bfr[nf], acc[mf][nf], 0, 0, 0);
    __syncthreads();   // frag reads done before next iter's staging
  }

  // Epilogue: D-frag row = lg*4 + r, col = lm
#pragma unroll
  for (int mf = 0; mf < 4; ++mf)
#pragma unroll
    for (int nf = 0; nf < 4; ++nf)
#pragma unroll
      for (int r = 0; r < 4; ++r) {
        const int row = bm + wm * 64 + mf * 16 + lg * 4 + r;
        const int col = bn + wn * 64 + nf * 16 + lm;
        store_out(C + (size_t)row * N + col, acc[mf][nf][r]);
      }
}

// ---------------------------------------------------------------------------
// Causal GQA flash attention, bf16 MFMA, SWAPPED QK^T (S^T = mfma(K,Q)) so
// each lane owns ONE q-row (col = lm) -> scalar m/l, in-lane row reduce.
// Blocks run longest-first (qt reversed) for LPT load balance.
// K staged via global_load_lds with pre-swizzled global source (rule #21):
// LDS[key*128 + off] holds K element (key, off ^ ((key&7)<<4)).
// ---------------------------------------------------------------------------
__global__ __launch_bounds__(256) void gqa_attn_mfma(
    const ushort* __restrict__ Q, const ushort* __restrict__ KV,
    ushort* __restrict__ Oat) {
  const int T = GQA_T, EQ = GQA_E, EKV = GQA_EKV;
  const int qt  = (int)gridDim.x - 1 - (int)blockIdx.x;  // longest first
  const int qt0 = qt * 64;
  const int hq  = blockIdx.y;
  const int b   = blockIdx.z;
  const int hkv = hq >> 2;

  __shared__ __align__(16) ushort Ks[64 * 64];       // [key][d], swizzled content
  __shared__ __align__(16) ushort Vt[64 * 64];       // [d][key], swizzled
  __shared__ __align__(16) ushort Ps[4 * 16 * 64];   // per-wave P^ [q][key], swizzled

  const int tid = threadIdx.x;
  const int w  = tid >> 6;
  const int l  = tid & 63;
  const int lm = l & 15;
  const int lg = l >> 4;

  // Q B-fragments: lane holds Q row (q = qt0+16w+lm), d-octet lg*8
  const size_t qrow = ((size_t)b * T + qt0 + 16 * w + lm) * EQ + hq * 64;
  const bf16x8 qa0 = *(const bf16x8*)(Q + qrow + lg * 8);
  const bf16x8 qa1 = *(const bf16x8*)(Q + qrow + 32 + lg * 8);

  f32x4 oacc[4];
#pragma unroll
  for (int nd = 0; nd < 4; ++nd)
#pragma unroll
    for (int r = 0; r < 4; ++r) oacc[nd][r] = 0.f;
  float m2 = -INFINITY, lsum = 0.f;        // log2-domain running max / sum
  const float SCL2 = 0.125f * 1.44269504088896f;   // scale * log2(e)

  const size_t kvbase = (size_t)b * T * EKV + hkv * 64;

  // K staging map (2 GLDS issues): issue c, lane l -> LDS flat
  // (c*4+w)*1024 + l*16 -> key = (c*4+w)*8 + (l>>3), in-row 16B slot (l&7).
  // Pre-swizzled source d-elems: ((l&7) ^ (l>>3)) * 8   (key&7 == l>>3)
  const int k_key  = w * 8 + (l >> 3);                 // c=0 key; c=1: +32
  const int k_srcd = (((l & 7) ^ (l >> 3)) * 8);
  char* KsB = (char*)Ks;
  char* VtB = (char*)Vt;
  char* PsB = (char*)Ps + w * 2048;
  char* ldsK0 = KsB + w * 1024;
  char* ldsK1 = KsB + (4 + w) * 1024;
  const int pswz = (lm & 7) << 4;

  const int nt = qt + 1;
  for (int t = 0; t < nt; ++t) {
    const int s0 = t * 64;
    const ushort* kg0 = KV + kvbase + (size_t)(s0 + k_key) * EKV + k_srcd;
    // V reg loads issued early (overlap prior PV under the barrier)
    int4 vr0 = *(const int4*)(KV + kvbase + 512 + (size_t)(s0 + l) * EKV + w * 8);
    int4 vr1 = *(const int4*)(KV + kvbase + 512 + (size_t)(s0 + l) * EKV + 32 + w * 8);
    __syncthreads();   // prior tile's LDS reads complete before overwrite
    GLDS16(kg0,                       ldsK0);
    GLDS16(kg0 + (size_t)32 * EKV,    ldsK1);
    // V tile transposed (scalar b16; row uniform per wave per j)
    {
      union { int4 v; ushort u[8]; } a, bq;
      a.v = vr0; bq.v = vr1;
#pragma unroll
      for (int j = 0; j < 8; ++j) {
        const int d0 = w * 8 + j;
        *(ushort*)(VtB + d0 * 128 + ((2 * l) ^ ((d0 & 7) << 4))) = a.u[j];
        const int d1 = 32 + w * 8 + j;
        *(ushort*)(VtB + d1 * 128 + ((2 * l) ^ ((d1 & 7) << 4))) = bq.u[j];
      }
    }
    __syncthreads();   // drains vmcnt(0) (K) + lgkm (V writes)

    // ---- S^T = K Q^T : lane holds q = qt0+16w+lm, keys nf*16+lg*4+{0..3} ----
    f32x4 sacc[4];
#pragma unroll
    for (int nf = 0; nf < 4; ++nf)
#pragma unroll
      for (int r = 0; r < 4; ++r) sacc[nf][r] = 0.f;
#pragma unroll
    for (int nf = 0; nf < 4; ++nf) {
      const int krow = nf * 16 + lm;
      const int swz = (krow & 7) << 4;
      bf16x8 kb0 = *(const bf16x8*)(KsB + krow * 128 + ((lg * 16) ^ swz));
      bf16x8 kb1 = *(const bf16x8*)(KsB + krow * 128 + ((64 + lg * 16) ^ swz));
      sacc[nf] = __builtin_amdgcn_mfma_f32_16x16x32_bf16(kb0, qa0, sacc[nf], 0, 0, 0);
      sacc[nf] = __builtin_amdgcn_mfma_f32_16x16x32_bf16(kb1, qa1, sacc[nf], 0, 0, 0);
    }

    // ---- scale to log2 domain (+ causal mask on diagonal tile) ----
    const int qg = qt0 + 16 * w + lm;
    if (t == nt - 1) {
#pragma unroll
      for (int nf = 0; nf < 4; ++nf)
#pragma unroll
        for (int r = 0; r < 4; ++r) {
          const int sg = s0 + nf * 16 + lg * 4 + r;
          const float sv = sacc[nf][r] * SCL2;
          sacc[nf][r] = (sg <= qg) ? sv : -INFINITY;
        }
    } else {
#pragma unroll
      for (int nf = 0; nf < 4; ++nf)
#pragma unroll
        for (int r = 0; r < 4; ++r) sacc[nf][r] *= SCL2;
    }

    // ---- online softmax: in-lane 16-reduce + 2 shfl over stride-16 lanes ----
    float mt = -INFINITY;
#pragma unroll
    for (int nf = 0; nf < 4; ++nf)
#pragma unroll
      for (int r = 0; r < 4; ++r) mt = fmaxf(mt, sacc[nf][r]);
    mt = fmaxf(mt, __shfl_xor(mt, 16));
    mt = fmaxf(mt, __shfl_xor(mt, 32));
    const float mnew = fmaxf(m2, mt);
    const float alpha = exp2f(m2 - mnew);   // first tile: exp2(-inf)=0
    m2 = mnew;
    float ssum = 0.f;
#pragma unroll
    for (int nf = 0; nf < 4; ++nf)
#pragma unroll
      for (int r = 0; r < 4; ++r) {
        const float p = exp2f(sacc[nf][r] - mnew);
        sacc[nf][r] = p;
        ssum += p;
      }
    ssum += __shfl_xor(ssum, 16);
    ssum += __shfl_xor(ssum, 32);
    lsum = lsum * alpha + ssum;

    // gather alpha for oacc rows (q = qt0+16w+lg*4+r, held by lane lg*4+r)
    float ar[4];
#pragma unroll
    for (int r = 0; r < 4; ++r) ar[r] = __shfl(alpha, lg * 4 + r);
#pragma unroll
    for (int nd = 0; nd < 4; ++nd)
#pragma unroll
      for (int r = 0; r < 4; ++r) oacc[nd][r] *= ar[r];

    // ---- P -> per-wave LDS: 4x b64 packed writes (keys nf*16+lg*4..+3) ----
#pragma unroll
    for (int nf = 0; nf < 4; ++nf) {
      union { uint2 v; __hip_bfloat162 h[2]; } pk;
      pk.h[0] = __float22bfloat162_rn(make_float2(sacc[nf][0], sacc[nf][1]));
      pk.h[1] = __float22bfloat162_rn(make_float2(sacc[nf][2], sacc[nf][3]));
      *(uint2*)(PsB + lm * 128 + ((nf * 32 + lg * 8) ^ pswz)) = pk.v;
    }

    // ---- O += P V : A-frag = P[q=lm][keys lg*8..+7 (+32)], B = V^T rows ----
    {
      bf16x8 pa0 = *(const bf16x8*)(PsB + lm * 128 + ((lg * 16) ^ pswz));
      bf16x8 pa1 = *(const bf16x8*)(PsB + lm * 128 + ((64 + lg * 16) ^ pswz));
#pragma unroll
      for (int nd = 0; nd < 4; ++nd) {
        const int vrow = nd * 16 + lm;
        const int vswz = (vrow & 7) << 4;
        bf16x8 vb0 = *(const bf16x8*)(VtB + vrow * 128 + ((lg * 16) ^ vswz));
        bf16x8 vb1 = *(const bf16x8*)(VtB + vrow * 128 + ((64 + lg * 16) ^ vswz));
        oacc[nd] = __builtin_amdgcn_mfma_f32_16x16x32_bf16(pa0, vb0, oacc[nd], 0, 0, 0);
        oacc[nd] = __builtin_amdgcn_mfma_f32_16x16x32_bf16(pa1, vb1, oacc[nd], 0, 0, 0);
      }
    }
  }

  // ---- epilogue: O / l (l for row lg*4+r gathered by shfl), bf16 out ----
  const float inv_own = 1.f / lsum;
  float ir[4];
#pragma unroll
  for (int r = 0; r < 4; ++r) ir[r] = __shfl(inv_own, lg * 4 + r);
  const size_t ob = ((size_t)b * T + qt0 + 16 * w + lg * 4) * EQ + hq * 64 + lm;
#pragma unroll
  for (int nd = 0; nd < 4; ++nd)
#pragma unroll
    for (int r = 0; r < 4; ++r)
      Oat[ob + (size_t)r * EQ + nd * 16] = f2b(oacc[nd][r] * ir[r]);
}

// ---------------------------------------------------------------------------
extern "C" void kernel_launch(void* const* d_in, const int* in_sizes, int n_in,
                              void* d_out, int out_size, void* d_ws, size_t ws_size,
                              hipStream_t stream) {
  const float* x   = (const float*)d_in[0];   // (B,T,E)
  const float* Wq  = (const float*)d_in[1];   // (E,E)
  const float* Wkv = (const float*)d_in[2];   // (1024,E)
  const float* Wo  = (const float*)d_in[3];   // (E,E)
  float* out = (float*)d_out;                  // (B,T,E) fp32

  // bf16 workspace layout (ushort elements); total ~76 MB
  ushort* xb   = (ushort*)d_ws;
  ushort* wqb  = xb   + (size_t)GQA_M * GQA_E;
  ushort* wkvb = wqb  + (size_t)GQA_E * GQA_E;
  ushort* wob  = wkvb + (size_t)GQA_EKV * GQA_E;
  ushort* qb   = wob  + (size_t)GQA_E * GQA_E;
  ushort* kvb  = qb   + (size_t)GQA_M * GQA_E;
  ushort* attb = kvb  + (size_t)GQA_M * GQA_EKV;

  cvt_f32_bf16<<<2048, 256, 0, stream>>>(x,   xb,   GQA_M * GQA_E / 4);
  cvt_f32_bf16<<<1024, 256, 0, stream>>>(Wq,  wqb,  GQA_E * GQA_E / 4);
  cvt_f32_bf16<<<512,  256, 0, stream>>>(Wkv, wkvb, GQA_EKV * GQA_E / 4);
  cvt_f32_bf16<<<1024, 256, 0, stream>>>(Wo,  wob,  GQA_E * GQA_E / 4);

  gemm_nt_bf16<ushort><<<dim3(GQA_E / 128, GQA_M / 128), 256, 0, stream>>>(
      xb, wqb, qb, GQA_M, GQA_E, GQA_E);
  gemm_nt_bf16<ushort><<<dim3(GQA_EKV / 128, GQA_M / 128), 256, 0, stream>>>(
      xb, wkvb, kvb, GQA_M, GQA_EKV, GQA_E);
  gqa_attn_mfma<<<dim3(GQA_T / 64, GQA_HQ, GQA_B), 256, 0, stream>>>(
      qb, kvb, attb);
  gemm_nt_bf16<float><<<dim3(GQA_E / 128, GQA_M / 128), 256, 0, stream>>>(
      attb, wob, out, GQA_M, GQA_E, GQA_E);
}

// Round 6
// 422.539 us; speedup vs baseline: 7.1302x; 1.0903x over previous
//
#include <hip/hip_runtime.h>
#include <hip/hip_bf16.h>
#include <math.h>

// Problem constants
#define GQA_B   2
#define GQA_T   2048
#define GQA_E   2048      // embed dim
#define GQA_HQ  32        // query heads
#define GQA_HKV 8         // kv heads
#define GQA_HD  64        // head dim
#define GQA_EKV 1024      // 2*HKV*HD
#define GQA_M   (GQA_B * GQA_T)   // 4096 rows

typedef short  bf16x8 __attribute__((ext_vector_type(8)));
typedef float  f32x4  __attribute__((ext_vector_type(4)));

// async global->LDS, 16B per lane; LDS dest = wave-uniform base + lane*16
#define GLDS16(gsrc, ldst)                                                 \
  __builtin_amdgcn_global_load_lds(                                       \
      (const __attribute__((address_space(1))) void*)(gsrc),              \
      (__attribute__((address_space(3))) void*)(ldst), 16, 0, 0)

// fp32 -> bf16 round-to-nearest-even (bit trick)
__device__ __forceinline__ ushort f2b(float f) {
  union { float f; unsigned u; } c; c.f = f;
  unsigned u = c.u;
  u += 0x7fffu + ((u >> 16) & 1u);
  return (ushort)(u >> 16);
}

// ---------------------------------------------------------------------------
// fp32 -> bf16 conversion, vectorized, grid-stride
// ---------------------------------------------------------------------------
__global__ __launch_bounds__(256) void cvt_f32_bf16(
    const float* __restrict__ src, ushort* __restrict__ dst, int n4) {
  int i = blockIdx.x * blockDim.x + threadIdx.x;
  const int stride = gridDim.x * blockDim.x;
  for (; i < n4; i += stride) {
    float4 v = *(const float4*)(src + (size_t)i * 4);
    ushort4 o;
    o.x = f2b(v.x); o.y = f2b(v.y); o.z = f2b(v.z); o.w = f2b(v.w);
    *(ushort4*)(dst + (size_t)i * 4) = o;
  }
}

// ---------------------------------------------------------------------------
// bf16 MFMA GEMM (NT): C(M,N) = A(M,K) @ B(N,K)^T. 128x128 tile, BK=32,
// 256 threads (4 waves, 2x2 of 64x64). DOUBLE-BUFFERED linear LDS staged via
// global_load_lds width=16; T3 minimal 2-phase: stage buf^1 first, compute
// buf, ONE barrier per K-step (prefetch latency hides under MFMA+ds_read).
// ---------------------------------------------------------------------------
__device__ __forceinline__ void store_out(ushort* p, float v) { *p = f2b(v); }
__device__ __forceinline__ void store_out(float* p, float v)  { *p = v; }

template <typename CT>
__global__ __launch_bounds__(256) void gemm_nt_bf16(
    const ushort* __restrict__ A, const ushort* __restrict__ B,
    CT* __restrict__ C, int M, int N, int K) {
  __shared__ __align__(16) ushort As[2 * 128 * 32];   // 16KB
  __shared__ __align__(16) ushort Bs[2 * 128 * 32];   // 16KB
  const int tid = threadIdx.x;
  const int l  = tid & 63;
  const int w  = tid >> 6;
  const int lm = l & 15;
  const int lg = l >> 4;
  const int wm = w & 1;
  const int wn = w >> 1;
  const int bm = blockIdx.y * 128;
  const int bn = blockIdx.x * 128;

  // staging: wave w covers rows [w*32, w*32+32); lane l -> row +(l>>2),
  // k-elems (l&3)*8. LDS flat byte = w*2048 (+1024 for 2nd 16 rows) + l*16.
  const int srow = w * 32 + (l >> 2);
  const int scol = (l & 3) * 8;
  const ushort* Ag = A + (size_t)(bm + srow) * K + scol;
  const ushort* Bg = B + (size_t)(bn + srow) * K + scol;
  char* ldsAw = (char*)As + w * 2048;
  char* ldsBw = (char*)Bs + w * 2048;

  f32x4 acc[4][4];
#pragma unroll
  for (int i = 0; i < 4; ++i)
#pragma unroll
    for (int j = 0; j < 4; ++j)
#pragma unroll
      for (int r = 0; r < 4; ++r) acc[i][j][r] = 0.f;

  const int nk = K >> 5;
  // prologue: stage k-step 0 into buffer 0
  GLDS16(Ag,                  ldsAw);
  GLDS16(Ag + (size_t)16 * K, ldsAw + 1024);
  GLDS16(Bg,                  ldsBw);
  GLDS16(Bg + (size_t)16 * K, ldsBw + 1024);
  __syncthreads();

  int cur = 0;
  for (int ks = 0; ks < nk; ++ks) {
    if (ks + 1 < nk) {   // prefetch next K-step into buf^1 (flies under MFMA)
      const size_t k0 = (size_t)(ks + 1) * 32;
      char* la = ldsAw + (cur ^ 1) * 8192;
      char* lb = ldsBw + (cur ^ 1) * 8192;
      GLDS16(Ag + k0,                  la);
      GLDS16(Ag + (size_t)16 * K + k0, la + 1024);
      GLDS16(Bg + k0,                  lb);
      GLDS16(Bg + (size_t)16 * K + k0, lb + 1024);
    }
    const ushort* Ac = As + cur * 4096;
    const ushort* Bc = Bs + cur * 4096;
    bf16x8 af[4], bfr[4];
#pragma unroll
    for (int mf = 0; mf < 4; ++mf)
      af[mf] = *(const bf16x8*)(Ac + (wm * 64 + mf * 16 + lm) * 32 + lg * 8);
#pragma unroll
    for (int nf = 0; nf < 4; ++nf)
      bfr[nf] = *(const bf16x8*)(Bc + (wn * 64 + nf * 16 + lm) * 32 + lg * 8);
#pragma unroll
    for (int mf = 0; mf < 4; ++mf)
#pragma unroll
      for (int nf = 0; nf < 4; ++nf)
        acc[mf][nf] = __builtin_amdgcn_mfma_f32_16x16x32_bf16(
            af[mf], bfr[nf], acc[mf][nf], 0, 0, 0);
    __syncthreads();   // reads of buf done + prefetch drained (vmcnt 0)
    cur ^= 1;
  }

  // Epilogue: D-frag row = lg*4 + r, col = lm
#pragma unroll
  for (int mf = 0; mf < 4; ++mf)
#pragma unroll
    for (int nf = 0; nf < 4; ++nf)
#pragma unroll
      for (int r = 0; r < 4; ++r) {
        const int row = bm + wm * 64 + mf * 16 + lg * 4 + r;
        const int col = bn + wn * 64 + nf * 16 + lm;
        store_out(C + (size_t)row * N + col, acc[mf][nf][r]);
      }
}

// ---------------------------------------------------------------------------
// Causal GQA flash attention, bf16 MFMA, swapped QK^T (lane owns one q-row),
// LPT (longest block first), DOUBLE-BUFFERED K (global_load_lds, rule-#21
// pre-swizzled source) and V (reg-staged transpose, issue-early/write-late).
// One barrier per KV tile; prefetch latency hides under QK^T+softmax+PV.
// ---------------------------------------------------------------------------
__global__ __launch_bounds__(256) void gqa_attn_mfma(
    const ushort* __restrict__ Q, const ushort* __restrict__ KV,
    ushort* __restrict__ Oat) {
  const int T = GQA_T, EQ = GQA_E, EKV = GQA_EKV;
  const int qt  = (int)gridDim.x - 1 - (int)blockIdx.x;  // longest first
  const int qt0 = qt * 64;
  const int hq  = blockIdx.y;
  const int b   = blockIdx.z;
  const int hkv = hq >> 2;

  __shared__ __align__(16) ushort Ks[2 * 64 * 64];   // 16KB [buf][key][d] swizzled
  __shared__ __align__(16) ushort Vt[2 * 64 * 64];   // 16KB [buf][d][key] swizzled
  __shared__ __align__(16) ushort Ps[4 * 16 * 64];   // 8KB per-wave P [q][key] swizzled

  const int tid = threadIdx.x;
  const int w  = tid >> 6;
  const int l  = tid & 63;
  const int lm = l & 15;
  const int lg = l >> 4;

  // Q B-fragments: lane holds Q row (q = qt0+16w+lm), d-octet lg*8
  const size_t qrow = ((size_t)b * T + qt0 + 16 * w + lm) * EQ + hq * 64;
  const bf16x8 qa0 = *(const bf16x8*)(Q + qrow + lg * 8);
  const bf16x8 qa1 = *(const bf16x8*)(Q + qrow + 32 + lg * 8);

  f32x4 oacc[4];
#pragma unroll
  for (int nd = 0; nd < 4; ++nd)
#pragma unroll
    for (int r = 0; r < 4; ++r) oacc[nd][r] = 0.f;
  float m2 = -INFINITY, lsum = 0.f;
  const float SCL2 = 0.125f * 1.44269504088896f;   // scale * log2(e)

  const size_t kvbase = (size_t)b * T * EKV + hkv * 64;

  // K staging map: issue c, lane l -> LDS flat (c*4+w)*1024 + l*16
  //   -> key = (c*4+w)*8 + (l>>3), 16B slot (l&7); source pre-swizzled.
  const int k_key  = w * 8 + (l >> 3);
  const int k_srcd = (((l & 7) ^ (l >> 3)) * 8);
  char* PsB = (char*)Ps + w * 2048;
  const int pswz = (lm & 7) << 4;
  const size_t vgbase = kvbase + 512 + (size_t)l * EKV + w * 8;

  const int nt = qt + 1;

  // ---- prologue: stage tile 0 into buffer 0 ----
  {
    const ushort* kg = KV + kvbase + (size_t)k_key * EKV + k_srcd;
    GLDS16(kg,                    (char*)Ks + w * 1024);
    GLDS16(kg + (size_t)32 * EKV, (char*)Ks + (4 + w) * 1024);
    int4 v0 = *(const int4*)(KV + vgbase);
    int4 v1 = *(const int4*)(KV + vgbase + 32);
    union { int4 v; ushort u[8]; } a, bq;
    a.v = v0; bq.v = v1;
#pragma unroll
    for (int j = 0; j < 8; ++j) {
      const int d0 = w * 8 + j;
      *(ushort*)((char*)Vt + d0 * 128 + ((2 * l) ^ ((d0 & 7) << 4))) = a.u[j];
      const int d1 = 32 + w * 8 + j;
      *(ushort*)((char*)Vt + d1 * 128 + ((2 * l) ^ ((d1 & 7) << 4))) = bq.u[j];
    }
  }
  __syncthreads();

  int cur = 0;
  for (int t = 0; t < nt; ++t) {
    const int s0 = t * 64;
    const bool pf = (t + 1 < nt);
    int4 nv0, nv1;
    if (pf) {   // issue next tile's loads FIRST (fly under this tile's compute)
      const size_t s1 = (size_t)(t + 1) * 64;
      nv0 = *(const int4*)(KV + vgbase + s1 * EKV);
      nv1 = *(const int4*)(KV + vgbase + s1 * EKV + 32);
      const ushort* kg = KV + kvbase + (s1 + k_key) * EKV + k_srcd;
      char* kb = (char*)Ks + (cur ^ 1) * 8192;
      GLDS16(kg,                    kb + w * 1024);
      GLDS16(kg + (size_t)32 * EKV, kb + (4 + w) * 1024);
    }
    const char* KsB = (const char*)Ks + cur * 8192;
    const char* VtB = (const char*)Vt + cur * 8192;

    // ---- S^T = K Q^T : lane holds q = qt0+16w+lm, keys nf*16+lg*4+{0..3} ----
    f32x4 sacc[4];
#pragma unroll
    for (int nf = 0; nf < 4; ++nf)
#pragma unroll
      for (int r = 0; r < 4; ++r) sacc[nf][r] = 0.f;
#pragma unroll
    for (int nf = 0; nf < 4; ++nf) {
      const int krow = nf * 16 + lm;
      const int swz = (krow & 7) << 4;
      bf16x8 kb0 = *(const bf16x8*)(KsB + krow * 128 + ((lg * 16) ^ swz));
      bf16x8 kb1 = *(const bf16x8*)(KsB + krow * 128 + ((64 + lg * 16) ^ swz));
      sacc[nf] = __builtin_amdgcn_mfma_f32_16x16x32_bf16(kb0, qa0, sacc[nf], 0, 0, 0);
      sacc[nf] = __builtin_amdgcn_mfma_f32_16x16x32_bf16(kb1, qa1, sacc[nf], 0, 0, 0);
    }

    // ---- causal mask (diagonal tile only, raw domain) ----
    const int qg = qt0 + 16 * w + lm;
    if (t == nt - 1) {
#pragma unroll
      for (int nf = 0; nf < 4; ++nf)
#pragma unroll
        for (int r = 0; r < 4; ++r) {
          const int sg = s0 + nf * 16 + lg * 4 + r;
          if (sg > qg) sacc[nf][r] = -INFINITY;
        }
    }

    // ---- online softmax; scale folded into exp2 via fma ----
    float mt = -INFINITY;
#pragma unroll
    for (int nf = 0; nf < 4; ++nf)
#pragma unroll
      for (int r = 0; r < 4; ++r) mt = fmaxf(mt, sacc[nf][r]);
    mt = fmaxf(mt, __shfl_xor(mt, 16));
    mt = fmaxf(mt, __shfl_xor(mt, 32));
    const float mnew = fmaxf(m2, mt * SCL2);
    const float alpha = exp2f(m2 - mnew);   // first tile: exp2(-inf)=0
    m2 = mnew;
    float ssum = 0.f;
#pragma unroll
    for (int nf = 0; nf < 4; ++nf)
#pragma unroll
      for (int r = 0; r < 4; ++r) {
        const float p = exp2f(fmaf(sacc[nf][r], SCL2, -mnew));
        sacc[nf][r] = p;
        ssum += p;
      }
    ssum += __shfl_xor(ssum, 16);
    ssum += __shfl_xor(ssum, 32);
    lsum = lsum * alpha + ssum;

    // gather alpha for oacc rows (q = qt0+16w+lg*4+r, held by lane lg*4+r)
    float ar[4];
#pragma unroll
    for (int r = 0; r < 4; ++r) ar[r] = __shfl(alpha, lg * 4 + r);
#pragma unroll
    for (int nd = 0; nd < 4; ++nd)
#pragma unroll
      for (int r = 0; r < 4; ++r) oacc[nd][r] *= ar[r];

    // ---- P -> per-wave LDS: 4x b64 packed writes ----
#pragma unroll
    for (int nf = 0; nf < 4; ++nf) {
      union { uint2 v; __hip_bfloat162 h[2]; } pk;
      pk.h[0] = __float22bfloat162_rn(make_float2(sacc[nf][0], sacc[nf][1]));
      pk.h[1] = __float22bfloat162_rn(make_float2(sacc[nf][2], sacc[nf][3]));
      *(uint2*)(PsB + lm * 128 + ((nf * 32 + lg * 8) ^ pswz)) = pk.v;
    }

    // ---- O += P V ----
    {
      bf16x8 pa0 = *(const bf16x8*)(PsB + lm * 128 + ((lg * 16) ^ pswz));
      bf16x8 pa1 = *(const bf16x8*)(PsB + lm * 128 + ((64 + lg * 16) ^ pswz));
#pragma unroll
      for (int nd = 0; nd < 4; ++nd) {
        const int vrow = nd * 16 + lm;
        const int vswz = (vrow & 7) << 4;
        bf16x8 vb0 = *(const bf16x8*)(VtB + vrow * 128 + ((lg * 16) ^ vswz));
        bf16x8 vb1 = *(const bf16x8*)(VtB + vrow * 128 + ((64 + lg * 16) ^ vswz));
        oacc[nd] = __builtin_amdgcn_mfma_f32_16x16x32_bf16(pa0, vb0, oacc[nd], 0, 0, 0);
        oacc[nd] = __builtin_amdgcn_mfma_f32_16x16x32_bf16(pa1, vb1, oacc[nd], 0, 0, 0);
      }
    }

    // ---- write-late: next tile's V regs -> Vt[buf^1] ----
    if (pf) {
      char* vb = (char*)Vt + (cur ^ 1) * 8192;
      union { int4 v; ushort u[8]; } a, bq;
      a.v = nv0; bq.v = nv1;
#pragma unroll
      for (int j = 0; j < 8; ++j) {
        const int d0 = w * 8 + j;
        *(ushort*)(vb + d0 * 128 + ((2 * l) ^ ((d0 & 7) << 4))) = a.u[j];
        const int d1 = 32 + w * 8 + j;
        *(ushort*)(vb + d1 * 128 + ((2 * l) ^ ((d1 & 7) << 4))) = bq.u[j];
      }
    }
    __syncthreads();   // drains K prefetch (vmcnt 0) + V writes; buf reads done
    cur ^= 1;
  }

  // ---- epilogue: O / l (l for row lg*4+r gathered by shfl), bf16 out ----
  const float inv_own = 1.f / lsum;
  float ir[4];
#pragma unroll
  for (int r = 0; r < 4; ++r) ir[r] = __shfl(inv_own, lg * 4 + r);
  const size_t ob = ((size_t)b * T + qt0 + 16 * w + lg * 4) * EQ + hq * 64 + lm;
#pragma unroll
  for (int nd = 0; nd < 4; ++nd)
#pragma unroll
    for (int r = 0; r < 4; ++r)
      Oat[ob + (size_t)r * EQ + nd * 16] = f2b(oacc[nd][r] * ir[r]);
}

// ---------------------------------------------------------------------------
extern "C" void kernel_launch(void* const* d_in, const int* in_sizes, int n_in,
                              void* d_out, int out_size, void* d_ws, size_t ws_size,
                              hipStream_t stream) {
  const float* x   = (const float*)d_in[0];   // (B,T,E)
  const float* Wq  = (const float*)d_in[1];   // (E,E)
  const float* Wkv = (const float*)d_in[2];   // (1024,E)
  const float* Wo  = (const float*)d_in[3];   // (E,E)
  float* out = (float*)d_out;                  // (B,T,E) fp32

  // bf16 workspace layout (ushort elements); total ~76 MB
  ushort* xb   = (ushort*)d_ws;
  ushort* wqb  = xb   + (size_t)GQA_M * GQA_E;
  ushort* wkvb = wqb  + (size_t)GQA_E * GQA_E;
  ushort* wob  = wkvb + (size_t)GQA_EKV * GQA_E;
  ushort* qb   = wob  + (size_t)GQA_E * GQA_E;
  ushort* kvb  = qb   + (size_t)GQA_M * GQA_E;
  ushort* attb = kvb  + (size_t)GQA_M * GQA_EKV;

  cvt_f32_bf16<<<2048, 256, 0, stream>>>(x,   xb,   GQA_M * GQA_E / 4);
  cvt_f32_bf16<<<1024, 256, 0, stream>>>(Wq,  wqb,  GQA_E * GQA_E / 4);
  cvt_f32_bf16<<<512,  256, 0, stream>>>(Wkv, wkvb, GQA_EKV * GQA_E / 4);
  cvt_f32_bf16<<<1024, 256, 0, stream>>>(Wo,  wob,  GQA_E * GQA_E / 4);

  gemm_nt_bf16<ushort><<<dim3(GQA_E / 128, GQA_M / 128), 256, 0, stream>>>(
      xb, wqb, qb, GQA_M, GQA_E, GQA_E);
  gemm_nt_bf16<ushort><<<dim3(GQA_EKV / 128, GQA_M / 128), 256, 0, stream>>>(
      xb, wkvb, kvb, GQA_M, GQA_EKV, GQA_E);
  gqa_attn_mfma<<<dim3(GQA_T / 64, GQA_HQ, GQA_B), 256, 0, stream>>>(
      qb, kvb, attb);
  gemm_nt_bf16<float><<<dim3(GQA_E / 128, GQA_M / 128), 256, 0, stream>>>(
      attb, wob, out, GQA_M, GQA_E, GQA_E);
}